// Round 1
// baseline (8729.501 us; speedup 1.0000x reference)
//
#include <hip/hip_runtime.h>
#include <math.h>

#define N_NODES 50000
#define N_EDGES 1600000
#define E_TOT   (N_EDGES + N_NODES)

__device__ __forceinline__ float lrelu02(float x) { return x > 0.f ? x : 0.2f * x; }
__device__ __forceinline__ float elu1(float x)    { return x > 0.f ? x : expm1f(x); }

// ---------------- GEMM: h[n, FOUT] = x[n, FIN] @ W[FIN, FOUT] ----------------
// block (64,4): 4 nodes per block, 64 output channels per blockIdx.y slice.
template<int FIN>
__global__ void gemm_kernel(const float* __restrict__ x, const float* __restrict__ W,
                            float* __restrict__ h, int FOUT) {
    __shared__ float Wl[FIN][64];
    const int tx = threadIdx.x, ty = threadIdx.y;
    const int f0 = blockIdx.y * 64;
    for (int i = ty * 64 + tx; i < FIN * 64; i += 256) {
        int k = i >> 6, f = i & 63;
        Wl[k][f] = (f0 + f < FOUT) ? W[(size_t)k * FOUT + f0 + f] : 0.f;
    }
    __syncthreads();
    int n = blockIdx.x * 4 + ty;
    if (n >= N_NODES) return;
    const float* xr = x + (size_t)n * FIN;
    float acc = 0.f;
#pragma unroll 8
    for (int k = 0; k < FIN; ++k) acc = fmaf(xr[k], Wl[k][tx], acc);
    int f = f0 + tx;
    if (f < FOUT) h[(size_t)n * FOUT + f] = acc;
}

// ---------------- per-(node,head) attention logits ----------------
__global__ void al_kernel(const float* __restrict__ h, const float* __restrict__ a_s,
                          const float* __restrict__ a_d, float* __restrict__ al_s,
                          float* __restrict__ al_d, int H, int C) {
    int i = blockIdx.x * blockDim.x + threadIdx.x;   // n*H + head
    if (i >= N_NODES * H) return;
    int n = i / H, hd = i % H;
    const float* hr = h + (size_t)n * H * C + hd * C;
    const float* as = a_s + hd * C;
    const float* ad = a_d + hd * C;
    float s1 = 0.f, s2 = 0.f;
    for (int c = 0; c < C; ++c) {
        float v = hr[c];
        s1 = fmaf(v, as[c], s1);
        s2 = fmaf(v, ad[c], s2);
    }
    al_s[i] = s1; al_d[i] = s2;
}

// ---------------- edge pass 1: softmax denominators ----------------
__global__ void edge_sum_kernel(const int* __restrict__ ei,
                                const float* __restrict__ al_s, const float* __restrict__ al_d,
                                float* __restrict__ sbuf, int H) {
    size_t tid = (size_t)blockIdx.x * blockDim.x + threadIdx.x;
    size_t total = (size_t)E_TOT * H;
    if (tid >= total) return;
    size_t i = tid / H;
    int hd = (int)(tid % H);
    int src, dst;
    if (i < N_EDGES) { src = ei[i]; dst = ei[N_EDGES + i]; }
    else             { src = dst = (int)(i - N_EDGES); }
    float e = al_s[src * H + hd] + al_d[dst * H + hd];
    atomicAdd(&sbuf[dst * H + hd], expf(lrelu02(e)));
}

// ---------------- edge pass 2: weighted scatter-aggregate ----------------
// one thread per (edge, 4-channel group)
__global__ void edge_agg_kernel(const int* __restrict__ ei,
                                const float* __restrict__ al_s, const float* __restrict__ al_d,
                                const float* __restrict__ sbuf, const float* __restrict__ h,
                                float* __restrict__ out, int H, int C) {
    const int HC = H * C;
    const int Q = HC / 4;
    size_t tid = (size_t)blockIdx.x * blockDim.x + threadIdx.x;
    size_t total = (size_t)E_TOT * Q;
    if (tid >= total) return;
    int q = (int)(tid % Q);
    size_t i = tid / Q;
    int src, dst;
    if (i < N_EDGES) { src = ei[i]; dst = ei[N_EDGES + i]; }
    else             { src = dst = (int)(i - N_EDGES); }
    int c0 = q * 4;
    int hd = c0 / C;
    float e = al_s[src * H + hd] + al_d[dst * H + hd];
    float w = expf(lrelu02(e)) / sbuf[dst * H + hd];
    const float4 hv = *(const float4*)(h + (size_t)src * HC + c0);
    float* op = out + (size_t)dst * HC + c0;
    atomicAdd(op + 0, hv.x * w);
    atomicAdd(op + 1, hv.y * w);
    atomicAdd(op + 2, hv.z * w);
    atomicAdd(op + 3, hv.w * w);
}

// ---------------- epilogue for concat layers: x_next = elu(out + b) ----------------
__global__ void elu_bias_kernel(const float* __restrict__ out, const float* __restrict__ b,
                                float* __restrict__ xn, size_t total, int HC) {
    size_t i = (size_t)blockIdx.x * blockDim.x + threadIdx.x;
    if (i >= total) return;
    int f = (int)(i % HC);
    xn[i] = elu1(out[i] + b[f]);
}

// ---------------- layer-3 epilogue: head-mean + bias + ELU + log_softmax ----------------
// one wave (64 lanes) per node; lanes 0..39 hold classes
__global__ void final_kernel(const float* __restrict__ out3, const float* __restrict__ b3,
                             float* __restrict__ y) {
    int node = blockIdx.x * 4 + (threadIdx.x >> 6);
    int lane = threadIdx.x & 63;
    if (node >= N_NODES) return;
    float v;
    if (lane < 40) {
        const float* p = out3 + (size_t)node * 240;
        float s = 0.f;
#pragma unroll
        for (int hh = 0; hh < 6; ++hh) s += p[hh * 40 + lane];
        v = s * (1.f / 6.f) + b3[lane];
        v = elu1(v);
    } else {
        v = -INFINITY;
    }
    float m = v;
#pragma unroll
    for (int o = 32; o > 0; o >>= 1) m = fmaxf(m, __shfl_xor(m, o));
    float ex = (lane < 40) ? expf(v - m) : 0.f;
    float ssum = ex;
#pragma unroll
    for (int o = 32; o > 0; o >>= 1) ssum += __shfl_xor(ssum, o);
    if (lane < 40) y[(size_t)node * 40 + lane] = v - m - logf(ssum);
}

// ---------------- host-side layer driver ----------------
static void run_gat_layer(const float* x, int FIN, const float* W,
                          const float* a_s, const float* a_d,
                          int H, int C, const int* ei,
                          float* h_buf, float* al_s, float* al_d,
                          float* s_buf, float* out_buf, hipStream_t stream) {
    const int HC = H * C;
    dim3 gblk(64, 4);
    dim3 ggrd((N_NODES + 3) / 4, (HC + 63) / 64);
    if (FIN == 128) gemm_kernel<128><<<ggrd, gblk, 0, stream>>>(x, W, h_buf, HC);
    else            gemm_kernel<64> <<<ggrd, gblk, 0, stream>>>(x, W, h_buf, HC);

    al_kernel<<<(N_NODES * H + 255) / 256, 256, 0, stream>>>(h_buf, a_s, a_d, al_s, al_d, H, C);

    hipMemsetAsync(s_buf, 0, (size_t)N_NODES * H * sizeof(float), stream);
    hipMemsetAsync(out_buf, 0, (size_t)N_NODES * HC * sizeof(float), stream);

    size_t t1 = (size_t)E_TOT * H;
    edge_sum_kernel<<<(t1 + 255) / 256, 256, 0, stream>>>(ei, al_s, al_d, s_buf, H);

    size_t t2 = (size_t)E_TOT * (HC / 4);
    edge_agg_kernel<<<(t2 + 255) / 256, 256, 0, stream>>>(ei, al_s, al_d, s_buf, h_buf, out_buf, H, C);
}

extern "C" void kernel_launch(void* const* d_in, const int* in_sizes, int n_in,
                              void* d_out, int out_size, void* d_ws, size_t ws_size,
                              hipStream_t stream) {
    const float* x   = (const float*)d_in[0];
    const int*   ei  = (const int*)d_in[1];   // [2, E]
    const float* W1  = (const float*)d_in[2];
    const float* a1s = (const float*)d_in[3];
    const float* a1d = (const float*)d_in[4];
    const float* b1  = (const float*)d_in[5];
    const float* W2  = (const float*)d_in[6];
    const float* a2s = (const float*)d_in[7];
    const float* a2d = (const float*)d_in[8];
    const float* b2  = (const float*)d_in[9];
    const float* W3  = (const float*)d_in[10];
    const float* a3s = (const float*)d_in[11];
    const float* a3d = (const float*)d_in[12];
    const float* b3  = (const float*)d_in[13];
    float* y = (float*)d_out;

    float* ws      = (float*)d_ws;
    float* h_buf   = ws;                  // N*240 = 12.0M floats
    float* out_buf = ws + 12000000;       // N*240 = 12.0M
    float* x_buf   = ws + 24000000;       // N*64  = 3.2M
    float* al_s    = ws + 27200000;       // N*6
    float* al_d    = ws + 27500000;       // N*6
    float* s_buf   = ws + 27800000;       // N*6   -> total 28.1M floats = 112.4 MB

    // ---- layer 1: 128 -> (4,16) concat ----
    run_gat_layer(x, 128, W1, a1s, a1d, 4, 16, ei, h_buf, al_s, al_d, s_buf, out_buf, stream);
    {
        size_t tot = (size_t)N_NODES * 64;
        elu_bias_kernel<<<(tot + 255) / 256, 256, 0, stream>>>(out_buf, b1, x_buf, tot, 64);
    }

    // ---- layer 2: 64 -> (4,16) concat ----
    run_gat_layer(x_buf, 64, W2, a2s, a2d, 4, 16, ei, h_buf, al_s, al_d, s_buf, out_buf, stream);
    {
        size_t tot = (size_t)N_NODES * 64;
        elu_bias_kernel<<<(tot + 255) / 256, 256, 0, stream>>>(out_buf, b2, x_buf, tot, 64);
    }

    // ---- layer 3: 64 -> (6,40) mean ----
    run_gat_layer(x_buf, 64, W3, a3s, a3d, 6, 40, ei, h_buf, al_s, al_d, s_buf, out_buf, stream);
    final_kernel<<<(N_NODES + 3) / 4, 256, 0, stream>>>(out_buf, b3, y);
}

// Round 2
// 1353.924 us; speedup vs baseline: 6.4476x; 6.4476x over previous
//
#include <hip/hip_runtime.h>
#include <math.h>

#define N_NODES 50000
#define N_EDGES 1600000

__device__ __forceinline__ float lrelu02(float x) { return x > 0.f ? x : 0.2f * x; }
__device__ __forceinline__ float elu1(float x)    { return x > 0.f ? x : expm1f(x); }

// ---------------- GEMM: h[n, FOUT] = x[n, FIN] @ W[FIN, FOUT] ----------------
template<int FIN>
__global__ void gemm_kernel(const float* __restrict__ x, const float* __restrict__ W,
                            float* __restrict__ h, int FOUT) {
    __shared__ float Wl[FIN][64];
    const int tx = threadIdx.x, ty = threadIdx.y;
    const int f0 = blockIdx.y * 64;
    for (int i = ty * 64 + tx; i < FIN * 64; i += 256) {
        int k = i >> 6, f = i & 63;
        Wl[k][f] = (f0 + f < FOUT) ? W[(size_t)k * FOUT + f0 + f] : 0.f;
    }
    __syncthreads();
    int n = blockIdx.x * 4 + ty;
    if (n >= N_NODES) return;
    const float* xr = x + (size_t)n * FIN;
    float acc = 0.f;
#pragma unroll 8
    for (int k = 0; k < FIN; ++k) acc = fmaf(xr[k], Wl[k][tx], acc);
    int f = f0 + tx;
    if (f < FOUT) h[(size_t)n * FOUT + f] = acc;
}

// ---------------- per-(node,head) attention logits ----------------
__global__ void al_kernel(const float* __restrict__ h, const float* __restrict__ a_s,
                          const float* __restrict__ a_d, float* __restrict__ al_s,
                          float* __restrict__ al_d, int H, int C) {
    int i = blockIdx.x * blockDim.x + threadIdx.x;   // n*H + head
    if (i >= N_NODES * H) return;
    int n = i / H, hd = i % H;
    const float* hr = h + (size_t)n * H * C + hd * C;
    const float* as = a_s + hd * C;
    const float* ad = a_d + hd * C;
    float s1 = 0.f, s2 = 0.f;
    for (int c = 0; c < C; ++c) {
        float v = hr[c];
        s1 = fmaf(v, as[c], s1);
        s2 = fmaf(v, ad[c], s2);
    }
    al_s[i] = s1; al_d[i] = s2;
}

// ---------------- CSR build ----------------
__global__ void deg_kernel(const int* __restrict__ ei, int* __restrict__ deg) {
    int e = blockIdx.x * 256 + threadIdx.x;
    if (e >= N_EDGES) return;
    atomicAdd(&deg[ei[N_EDGES + e]], 1);
}

// one block of 1024 threads scans the 50k-degree array; deg becomes the cursor
__global__ void scan_kernel(int* __restrict__ deg, int* __restrict__ rowptr) {
    __shared__ int sums[1024];
    int t = threadIdx.x;
    const int PER = (N_NODES + 1023) / 1024;  // 49
    int base = t * PER;
    int s = 0;
    for (int i = 0; i < PER; ++i) { int idx = base + i; if (idx < N_NODES) s += deg[idx]; }
    sums[t] = s;
    __syncthreads();
    for (int off = 1; off < 1024; off <<= 1) {
        int v = sums[t];
        int add = (t >= off) ? sums[t - off] : 0;
        __syncthreads();
        sums[t] = v + add;
        __syncthreads();
    }
    if (t == 0) rowptr[N_NODES] = sums[1023];
    int run = (t == 0) ? 0 : sums[t - 1];
    for (int i = 0; i < PER; ++i) {
        int idx = base + i;
        if (idx < N_NODES) {
            int d = deg[idx];
            rowptr[idx] = run;
            deg[idx] = run;       // cursor starts at row begin
            run += d;
        }
    }
}

__global__ void scatter_kernel(const int* __restrict__ ei, int* __restrict__ cursor,
                               unsigned short* __restrict__ csr_src) {
    int e = blockIdx.x * 256 + threadIdx.x;
    if (e >= N_EDGES) return;
    int src = ei[e], dst = ei[N_EDGES + e];
    int pos = atomicAdd(&cursor[dst], 1);
    csr_src[pos] = (unsigned short)src;   // N_NODES < 65536
}

// ---------------- gather aggregation, one wave per node ----------------
// HC = 64 (H=4, C=16): lane = channel; fused bias + ELU epilogue.
__global__ void agg64_kernel(const int* __restrict__ rowptr, const unsigned short* __restrict__ csr_src,
                             const float* __restrict__ al_s, const float* __restrict__ al_d,
                             const float* __restrict__ h, const float* __restrict__ b,
                             float* __restrict__ xn) {
    int node = blockIdx.x * 4 + (threadIdx.x >> 6);
    int lane = threadIdx.x & 63;
    if (node >= N_NODES) return;
    int hd = lane >> 4;                           // C = 16
    float ald = al_d[node * 4 + hd];
    int beg = rowptr[node], end = rowptr[node + 1];
    // self loop
    float w = expf(lrelu02(al_s[node * 4 + hd] + ald));
    float denom = w;
    float acc = w * h[(size_t)node * 64 + lane];
    for (int j = beg; j < end; ++j) {
        int src = csr_src[j];
        float ww = expf(lrelu02(al_s[src * 4 + hd] + ald));
        denom += ww;
        acc = fmaf(ww, h[(size_t)src * 64 + lane], acc);
    }
    xn[(size_t)node * 64 + lane] = elu1(acc / denom + b[lane]);
}

// HC = 240 (H=6, C=40): lane handles 4 channels; lanes 60..63 idle on stores.
__global__ void agg240_kernel(const int* __restrict__ rowptr, const unsigned short* __restrict__ csr_src,
                              const float* __restrict__ al_s, const float* __restrict__ al_d,
                              const float* __restrict__ h, float* __restrict__ out) {
    int node = blockIdx.x * 4 + (threadIdx.x >> 6);
    int lane = threadIdx.x & 63;
    if (node >= N_NODES) return;
    bool act = lane < 60;
    int c0 = act ? lane * 4 : 0;
    int hd = c0 / 40;
    float ald = al_d[node * 6 + hd];
    int beg = rowptr[node], end = rowptr[node + 1];
    float w = expf(lrelu02(al_s[node * 6 + hd] + ald));
    float denom = w;
    float4 hv = *(const float4*)(h + (size_t)node * 240 + c0);
    float4 acc;
    acc.x = w * hv.x; acc.y = w * hv.y; acc.z = w * hv.z; acc.w = w * hv.w;
    for (int j = beg; j < end; ++j) {
        int src = csr_src[j];
        float ww = expf(lrelu02(al_s[src * 6 + hd] + ald));
        denom += ww;
        hv = *(const float4*)(h + (size_t)src * 240 + c0);
        acc.x = fmaf(ww, hv.x, acc.x);
        acc.y = fmaf(ww, hv.y, acc.y);
        acc.z = fmaf(ww, hv.z, acc.z);
        acc.w = fmaf(ww, hv.w, acc.w);
    }
    if (act) {
        float r = 1.f / denom;
        float* op = out + (size_t)node * 240 + c0;
        op[0] = acc.x * r; op[1] = acc.y * r; op[2] = acc.z * r; op[3] = acc.w * r;
    }
}

// ---------------- layer-3 epilogue: head-mean + bias + ELU + log_softmax ----------------
__global__ void final_kernel(const float* __restrict__ out3, const float* __restrict__ b3,
                             float* __restrict__ y) {
    int node = blockIdx.x * 4 + (threadIdx.x >> 6);
    int lane = threadIdx.x & 63;
    if (node >= N_NODES) return;
    float v;
    if (lane < 40) {
        const float* p = out3 + (size_t)node * 240;
        float s = 0.f;
#pragma unroll
        for (int hh = 0; hh < 6; ++hh) s += p[hh * 40 + lane];
        v = s * (1.f / 6.f) + b3[lane];
        v = elu1(v);
    } else {
        v = -INFINITY;
    }
    float m = v;
#pragma unroll
    for (int o = 32; o > 0; o >>= 1) m = fmaxf(m, __shfl_xor(m, o));
    float ex = (lane < 40) ? expf(v - m) : 0.f;
    float ssum = ex;
#pragma unroll
    for (int o = 32; o > 0; o >>= 1) ssum += __shfl_xor(ssum, o);
    if (lane < 40) y[(size_t)node * 40 + lane] = v - m - logf(ssum);
}

extern "C" void kernel_launch(void* const* d_in, const int* in_sizes, int n_in,
                              void* d_out, int out_size, void* d_ws, size_t ws_size,
                              hipStream_t stream) {
    const float* x   = (const float*)d_in[0];
    const int*   ei  = (const int*)d_in[1];   // [2, E]
    const float* W1  = (const float*)d_in[2];
    const float* a1s = (const float*)d_in[3];
    const float* a1d = (const float*)d_in[4];
    const float* b1  = (const float*)d_in[5];
    const float* W2  = (const float*)d_in[6];
    const float* a2s = (const float*)d_in[7];
    const float* a2d = (const float*)d_in[8];
    const float* b2  = (const float*)d_in[9];
    const float* W3  = (const float*)d_in[10];
    const float* a3s = (const float*)d_in[11];
    const float* a3d = (const float*)d_in[12];
    const float* b3  = (const float*)d_in[13];
    float* y = (float*)d_out;

    float* ws      = (float*)d_ws;
    float* h_buf   = ws;                                  // 12,000,000 floats
    float* out_buf = ws + 12000000;                       // 12,000,000
    float* x_buf   = ws + 24000000;                       //  3,200,000
    float* al_s    = ws + 27200000;                       //    300,000
    float* al_d    = ws + 27500000;                       //    300,000
    int*   deg     = (int*)(ws + 27800000);               //     50,000 (becomes cursor)
    int*   rowptr  = (int*)(ws + 27850000);               //     50,001 (pad to 27,900,008)
    unsigned short* csr_src = (unsigned short*)(ws + 27900008); // 1.6M ushort = 800,000 slots
    // total: 28,700,008 floats = 114.8 MB

    // ---- CSR build (once; shared by all 3 layers) ----
    hipMemsetAsync(deg, 0, N_NODES * sizeof(int), stream);
    deg_kernel<<<(N_EDGES + 255) / 256, 256, 0, stream>>>(ei, deg);
    scan_kernel<<<1, 1024, 0, stream>>>(deg, rowptr);
    scatter_kernel<<<(N_EDGES + 255) / 256, 256, 0, stream>>>(ei, deg, csr_src);

    const int agg_grid = (N_NODES + 3) / 4;

    // ---- layer 1: 128 -> (4,16) concat ----
    {
        dim3 gblk(64, 4), ggrd((N_NODES + 3) / 4, 1);
        gemm_kernel<128><<<ggrd, gblk, 0, stream>>>(x, W1, h_buf, 64);
        al_kernel<<<(N_NODES * 4 + 255) / 256, 256, 0, stream>>>(h_buf, a1s, a1d, al_s, al_d, 4, 16);
        agg64_kernel<<<agg_grid, 256, 0, stream>>>(rowptr, csr_src, al_s, al_d, h_buf, b1, x_buf);
    }

    // ---- layer 2: 64 -> (4,16) concat ----
    {
        dim3 gblk(64, 4), ggrd((N_NODES + 3) / 4, 1);
        gemm_kernel<64><<<ggrd, gblk, 0, stream>>>(x_buf, W2, h_buf, 64);
        al_kernel<<<(N_NODES * 4 + 255) / 256, 256, 0, stream>>>(h_buf, a2s, a2d, al_s, al_d, 4, 16);
        agg64_kernel<<<agg_grid, 256, 0, stream>>>(rowptr, csr_src, al_s, al_d, h_buf, b2, x_buf);
    }

    // ---- layer 3: 64 -> (6,40) mean ----
    {
        dim3 gblk(64, 4), ggrd((N_NODES + 3) / 4, (240 + 63) / 64);
        gemm_kernel<64><<<ggrd, gblk, 0, stream>>>(x_buf, W3, h_buf, 240);
        al_kernel<<<(N_NODES * 6 + 255) / 256, 256, 0, stream>>>(h_buf, a3s, a3d, al_s, al_d, 6, 40);
        agg240_kernel<<<agg_grid, 256, 0, stream>>>(rowptr, csr_src, al_s, al_d, h_buf, out_buf);
        final_kernel<<<agg_grid, 256, 0, stream>>>(out_buf, b3, y);
    }
}

// Round 3
// 1037.968 us; speedup vs baseline: 8.4102x; 1.3044x over previous
//
#include <hip/hip_runtime.h>
#include <math.h>

#define N_NODES 50000
#define N_EDGES 1600000

__device__ __forceinline__ float lrelu02(float x) { return x > 0.f ? x : 0.2f * x; }
__device__ __forceinline__ float elu1(float x)    { return x > 0.f ? x : expm1f(x); }

// bf16 helpers (RNE pack)
__device__ __forceinline__ unsigned short f2bf(float f) {
    unsigned int u = __float_as_uint(f);
    return (unsigned short)((u + 0x7fffu + ((u >> 16) & 1u)) >> 16);
}
__device__ __forceinline__ float bf2f(unsigned short s) {
    return __uint_as_float((unsigned int)s << 16);
}
__device__ __forceinline__ float2 bfp2(unsigned int u) {
    float2 r;
    r.x = __uint_as_float(u << 16);
    r.y = __uint_as_float(u & 0xffff0000u);
    return r;
}

// ---------------- GEMM: h_bf[n, FOUT] = bf16(x[n, FIN] @ W[FIN, FOUT]) ----------------
template<int FIN>
__global__ void gemm_kernel(const float* __restrict__ x, const float* __restrict__ W,
                            unsigned short* __restrict__ h, int FOUT) {
    __shared__ float Wl[FIN][64];
    const int tx = threadIdx.x, ty = threadIdx.y;
    const int f0 = blockIdx.y * 64;
    for (int i = ty * 64 + tx; i < FIN * 64; i += 256) {
        int k = i >> 6, f = i & 63;
        Wl[k][f] = (f0 + f < FOUT) ? W[(size_t)k * FOUT + f0 + f] : 0.f;
    }
    __syncthreads();
    int n = blockIdx.x * 4 + ty;
    if (n >= N_NODES) return;
    const float* xr = x + (size_t)n * FIN;
    float acc = 0.f;
#pragma unroll 8
    for (int k = 0; k < FIN; ++k) acc = fmaf(xr[k], Wl[k][tx], acc);
    int f = f0 + tx;
    if (f < FOUT) h[(size_t)n * FOUT + f] = f2bf(acc);
}

// ---------------- per-(node,head) attention logits ----------------
__global__ void al_kernel(const unsigned short* __restrict__ h, const float* __restrict__ a_s,
                          const float* __restrict__ a_d, float* __restrict__ al_s,
                          float* __restrict__ al_d, int H, int C) {
    int i = blockIdx.x * blockDim.x + threadIdx.x;   // n*H + head
    if (i >= N_NODES * H) return;
    int n = i / H, hd = i % H;
    const unsigned short* hr = h + (size_t)n * H * C + hd * C;
    const float* as = a_s + hd * C;
    const float* ad = a_d + hd * C;
    float s1 = 0.f, s2 = 0.f;
    for (int c = 0; c < C; ++c) {
        float v = bf2f(hr[c]);
        s1 = fmaf(v, as[c], s1);
        s2 = fmaf(v, ad[c], s2);
    }
    al_s[i] = s1; al_d[i] = s2;
}

// ---------------- CSR build ----------------
__global__ void deg_kernel(const int* __restrict__ ei, int* __restrict__ deg) {
    int e = blockIdx.x * 256 + threadIdx.x;
    if (e >= N_EDGES) return;
    atomicAdd(&deg[ei[N_EDGES + e]], 1);
}

__global__ void scan_kernel(int* __restrict__ deg, int* __restrict__ rowptr) {
    __shared__ int sums[1024];
    int t = threadIdx.x;
    const int PER = (N_NODES + 1023) / 1024;  // 49
    int base = t * PER;
    int s = 0;
    for (int i = 0; i < PER; ++i) { int idx = base + i; if (idx < N_NODES) s += deg[idx]; }
    sums[t] = s;
    __syncthreads();
    for (int off = 1; off < 1024; off <<= 1) {
        int v = sums[t];
        int add = (t >= off) ? sums[t - off] : 0;
        __syncthreads();
        sums[t] = v + add;
        __syncthreads();
    }
    if (t == 0) rowptr[N_NODES] = sums[1023];
    int run = (t == 0) ? 0 : sums[t - 1];
    for (int i = 0; i < PER; ++i) {
        int idx = base + i;
        if (idx < N_NODES) {
            int d = deg[idx];
            rowptr[idx] = run;
            deg[idx] = run;       // cursor starts at row begin
            run += d;
        }
    }
}

__global__ void scatter_kernel(const int* __restrict__ ei, int* __restrict__ cursor,
                               unsigned short* __restrict__ csr_src) {
    int e = blockIdx.x * 256 + threadIdx.x;
    if (e >= N_EDGES) return;
    int src = ei[e], dst = ei[N_EDGES + e];
    int pos = atomicAdd(&cursor[dst], 1);
    csr_src[pos] = (unsigned short)src;   // N_NODES < 65536
}

// ---------------- gather aggregation, one wave per node ----------------
// HC = 64 (H=4, C=16): lane = channel; fused bias + ELU epilogue. 4x unrolled.
__global__ void agg64_kernel(const int* __restrict__ rowptr, const unsigned short* __restrict__ csr_src,
                             const float* __restrict__ al_s, const float* __restrict__ al_d,
                             const unsigned short* __restrict__ hb, const float* __restrict__ b,
                             float* __restrict__ xn) {
    int node = blockIdx.x * 4 + (threadIdx.x >> 6);
    int lane = threadIdx.x & 63;
    if (node >= N_NODES) return;
    int hd = lane >> 4;                           // C = 16
    float ald = al_d[node * 4 + hd];
    int beg = rowptr[node], end = rowptr[node + 1];
    // self loop
    float w = expf(lrelu02(al_s[node * 4 + hd] + ald));
    float denom = w;
    float acc = w * bf2f(hb[(size_t)node * 64 + lane]);
    int j = beg;
    for (; j + 4 <= end; j += 4) {
        int s0 = csr_src[j], s1 = csr_src[j + 1], s2 = csr_src[j + 2], s3 = csr_src[j + 3];
        unsigned short q0 = hb[(size_t)s0 * 64 + lane];
        unsigned short q1 = hb[(size_t)s1 * 64 + lane];
        unsigned short q2 = hb[(size_t)s2 * 64 + lane];
        unsigned short q3 = hb[(size_t)s3 * 64 + lane];
        float w0 = expf(lrelu02(al_s[s0 * 4 + hd] + ald));
        float w1 = expf(lrelu02(al_s[s1 * 4 + hd] + ald));
        float w2 = expf(lrelu02(al_s[s2 * 4 + hd] + ald));
        float w3 = expf(lrelu02(al_s[s3 * 4 + hd] + ald));
        denom += (w0 + w1) + (w2 + w3);
        acc = fmaf(w0, bf2f(q0), acc);
        acc = fmaf(w1, bf2f(q1), acc);
        acc = fmaf(w2, bf2f(q2), acc);
        acc = fmaf(w3, bf2f(q3), acc);
    }
    for (; j < end; ++j) {
        int s0 = csr_src[j];
        float w0 = expf(lrelu02(al_s[s0 * 4 + hd] + ald));
        denom += w0;
        acc = fmaf(w0, bf2f(hb[(size_t)s0 * 64 + lane]), acc);
    }
    xn[(size_t)node * 64 + lane] = elu1(acc / denom + b[lane]);
}

// HC = 240 (H=6, C=40): lane handles 4 channels (8B bf16 gather); 4x unrolled.
__global__ void agg240_kernel(const int* __restrict__ rowptr, const unsigned short* __restrict__ csr_src,
                              const float* __restrict__ al_s, const float* __restrict__ al_d,
                              const unsigned short* __restrict__ hb, float* __restrict__ out) {
    int node = blockIdx.x * 4 + (threadIdx.x >> 6);
    int lane = threadIdx.x & 63;
    if (node >= N_NODES) return;
    bool act = lane < 60;
    int c0 = act ? lane * 4 : 0;
    int hd = c0 / 40;
    float ald = al_d[node * 6 + hd];
    int beg = rowptr[node], end = rowptr[node + 1];
    float w = expf(lrelu02(al_s[node * 6 + hd] + ald));
    float denom = w;
    float4 acc;
    {
        uint2 q = *(const uint2*)(hb + (size_t)node * 240 + c0);
        float2 ab = bfp2(q.x), cd = bfp2(q.y);
        acc.x = w * ab.x; acc.y = w * ab.y; acc.z = w * cd.x; acc.w = w * cd.y;
    }
    int j = beg;
    for (; j + 4 <= end; j += 4) {
        int s0 = csr_src[j], s1 = csr_src[j + 1], s2 = csr_src[j + 2], s3 = csr_src[j + 3];
        uint2 q0 = *(const uint2*)(hb + (size_t)s0 * 240 + c0);
        uint2 q1 = *(const uint2*)(hb + (size_t)s1 * 240 + c0);
        uint2 q2 = *(const uint2*)(hb + (size_t)s2 * 240 + c0);
        uint2 q3 = *(const uint2*)(hb + (size_t)s3 * 240 + c0);
        float w0 = expf(lrelu02(al_s[s0 * 6 + hd] + ald));
        float w1 = expf(lrelu02(al_s[s1 * 6 + hd] + ald));
        float w2 = expf(lrelu02(al_s[s2 * 6 + hd] + ald));
        float w3 = expf(lrelu02(al_s[s3 * 6 + hd] + ald));
        denom += (w0 + w1) + (w2 + w3);
        float2 ab, cd;
        ab = bfp2(q0.x); cd = bfp2(q0.y);
        acc.x = fmaf(w0, ab.x, acc.x); acc.y = fmaf(w0, ab.y, acc.y);
        acc.z = fmaf(w0, cd.x, acc.z); acc.w = fmaf(w0, cd.y, acc.w);
        ab = bfp2(q1.x); cd = bfp2(q1.y);
        acc.x = fmaf(w1, ab.x, acc.x); acc.y = fmaf(w1, ab.y, acc.y);
        acc.z = fmaf(w1, cd.x, acc.z); acc.w = fmaf(w1, cd.y, acc.w);
        ab = bfp2(q2.x); cd = bfp2(q2.y);
        acc.x = fmaf(w2, ab.x, acc.x); acc.y = fmaf(w2, ab.y, acc.y);
        acc.z = fmaf(w2, cd.x, acc.z); acc.w = fmaf(w2, cd.y, acc.w);
        ab = bfp2(q3.x); cd = bfp2(q3.y);
        acc.x = fmaf(w3, ab.x, acc.x); acc.y = fmaf(w3, ab.y, acc.y);
        acc.z = fmaf(w3, cd.x, acc.z); acc.w = fmaf(w3, cd.y, acc.w);
    }
    for (; j < end; ++j) {
        int s0 = csr_src[j];
        uint2 q0 = *(const uint2*)(hb + (size_t)s0 * 240 + c0);
        float w0 = expf(lrelu02(al_s[s0 * 6 + hd] + ald));
        denom += w0;
        float2 ab = bfp2(q0.x), cd = bfp2(q0.y);
        acc.x = fmaf(w0, ab.x, acc.x); acc.y = fmaf(w0, ab.y, acc.y);
        acc.z = fmaf(w0, cd.x, acc.z); acc.w = fmaf(w0, cd.y, acc.w);
    }
    if (act) {
        float r = 1.f / denom;
        float* op = out + (size_t)node * 240 + c0;
        op[0] = acc.x * r; op[1] = acc.y * r; op[2] = acc.z * r; op[3] = acc.w * r;
    }
}

// ---------------- layer-3 epilogue: head-mean + bias + ELU + log_softmax ----------------
__global__ void final_kernel(const float* __restrict__ out3, const float* __restrict__ b3,
                             float* __restrict__ y) {
    int node = blockIdx.x * 4 + (threadIdx.x >> 6);
    int lane = threadIdx.x & 63;
    if (node >= N_NODES) return;
    float v;
    if (lane < 40) {
        const float* p = out3 + (size_t)node * 240;
        float s = 0.f;
#pragma unroll
        for (int hh = 0; hh < 6; ++hh) s += p[hh * 40 + lane];
        v = s * (1.f / 6.f) + b3[lane];
        v = elu1(v);
    } else {
        v = -INFINITY;
    }
    float m = v;
#pragma unroll
    for (int o = 32; o > 0; o >>= 1) m = fmaxf(m, __shfl_xor(m, o));
    float ex = (lane < 40) ? expf(v - m) : 0.f;
    float ssum = ex;
#pragma unroll
    for (int o = 32; o > 0; o >>= 1) ssum += __shfl_xor(ssum, o);
    if (lane < 40) y[(size_t)node * 40 + lane] = v - m - logf(ssum);
}

extern "C" void kernel_launch(void* const* d_in, const int* in_sizes, int n_in,
                              void* d_out, int out_size, void* d_ws, size_t ws_size,
                              hipStream_t stream) {
    const float* x   = (const float*)d_in[0];
    const int*   ei  = (const int*)d_in[1];   // [2, E]
    const float* W1  = (const float*)d_in[2];
    const float* a1s = (const float*)d_in[3];
    const float* a1d = (const float*)d_in[4];
    const float* b1  = (const float*)d_in[5];
    const float* W2  = (const float*)d_in[6];
    const float* a2s = (const float*)d_in[7];
    const float* a2d = (const float*)d_in[8];
    const float* b2  = (const float*)d_in[9];
    const float* W3  = (const float*)d_in[10];
    const float* a3s = (const float*)d_in[11];
    const float* a3d = (const float*)d_in[12];
    const float* b3  = (const float*)d_in[13];
    float* y = (float*)d_out;

    float* ws      = (float*)d_ws;
    unsigned short* h_bf = (unsigned short*)ws;           // 12,000,000 ushort (= 6.0M floats)
    float* out_buf = ws + 6000000;                        // 12,000,000 floats
    float* x_buf   = ws + 18000000;                       //  3,200,000
    float* al_s    = ws + 21200000;                       //    300,000
    float* al_d    = ws + 21500000;                       //    300,000
    int*   deg     = (int*)(ws + 21800000);               //     50,000 (becomes cursor)
    int*   rowptr  = (int*)(ws + 21850000);               //     50,001
    unsigned short* csr_src = (unsigned short*)(ws + 21900008); // 1.6M ushort
    // total: 22,700,008 floats = 90.8 MB

    // ---- CSR build (once; shared by all 3 layers) ----
    hipMemsetAsync(deg, 0, N_NODES * sizeof(int), stream);
    deg_kernel<<<(N_EDGES + 255) / 256, 256, 0, stream>>>(ei, deg);
    scan_kernel<<<1, 1024, 0, stream>>>(deg, rowptr);
    scatter_kernel<<<(N_EDGES + 255) / 256, 256, 0, stream>>>(ei, deg, csr_src);

    const int agg_grid = (N_NODES + 3) / 4;

    // ---- layer 1: 128 -> (4,16) concat ----
    {
        dim3 gblk(64, 4), ggrd((N_NODES + 3) / 4, 1);
        gemm_kernel<128><<<ggrd, gblk, 0, stream>>>(x, W1, h_bf, 64);
        al_kernel<<<(N_NODES * 4 + 255) / 256, 256, 0, stream>>>(h_bf, a1s, a1d, al_s, al_d, 4, 16);
        agg64_kernel<<<agg_grid, 256, 0, stream>>>(rowptr, csr_src, al_s, al_d, h_bf, b1, x_buf);
    }

    // ---- layer 2: 64 -> (4,16) concat ----
    {
        dim3 gblk(64, 4), ggrd((N_NODES + 3) / 4, 1);
        gemm_kernel<64><<<ggrd, gblk, 0, stream>>>(x_buf, W2, h_bf, 64);
        al_kernel<<<(N_NODES * 4 + 255) / 256, 256, 0, stream>>>(h_bf, a2s, a2d, al_s, al_d, 4, 16);
        agg64_kernel<<<agg_grid, 256, 0, stream>>>(rowptr, csr_src, al_s, al_d, h_bf, b2, x_buf);
    }

    // ---- layer 3: 64 -> (6,40) mean ----
    {
        dim3 gblk(64, 4), ggrd((N_NODES + 3) / 4, (240 + 63) / 64);
        gemm_kernel<64><<<ggrd, gblk, 0, stream>>>(x_buf, W3, h_bf, 240);
        al_kernel<<<(N_NODES * 6 + 255) / 256, 256, 0, stream>>>(h_bf, a3s, a3d, al_s, al_d, 6, 40);
        agg240_kernel<<<agg_grid, 256, 0, stream>>>(rowptr, csr_src, al_s, al_d, h_bf, out_buf);
        final_kernel<<<agg_grid, 256, 0, stream>>>(out_buf, b3, y);
    }
}

// Round 4
// 977.284 us; speedup vs baseline: 8.9324x; 1.0621x over previous
//
#include <hip/hip_runtime.h>
#include <math.h>

#define N_NODES 50000
#define N_EDGES 1600000

__device__ __forceinline__ float lrelu02(float x) { return x > 0.f ? x : 0.2f * x; }
__device__ __forceinline__ float elu1(float x)    { return x > 0.f ? x : expm1f(x); }

// bf16 helpers (RNE pack)
__device__ __forceinline__ unsigned short f2bf(float f) {
    unsigned int u = __float_as_uint(f);
    return (unsigned short)((u + 0x7fffu + ((u >> 16) & 1u)) >> 16);
}
__device__ __forceinline__ float bf2f(unsigned short s) {
    return __uint_as_float((unsigned int)s << 16);
}
__device__ __forceinline__ float2 bfp2(unsigned int u) {
    float2 r;
    r.x = __uint_as_float(u << 16);
    r.y = __uint_as_float(u & 0xffff0000u);
    return r;
}

// ---------------- GEMM: h_bf[n, FOUT] = bf16(x[n, FIN] @ W[FIN, FOUT]) ----------------
// block (64,4); each thread: 8 nodes x 1 channel -> 8 independent FMA chains,
// 1 ds_read per 8 FMAs, x rows via broadcast float4 loads.
template<int FIN>
__global__ void gemm_kernel(const float* __restrict__ x, const float* __restrict__ W,
                            unsigned short* __restrict__ h, int FOUT) {
    __shared__ float Wl[FIN][64];
    const int tx = threadIdx.x, ty = threadIdx.y;
    const int f0 = blockIdx.y * 64;
    for (int i = ty * 64 + tx; i < FIN * 64; i += 256) {
        int k = i >> 6, f = i & 63;
        Wl[k][f] = (f0 + f < FOUT) ? W[(size_t)k * FOUT + f0 + f] : 0.f;
    }
    __syncthreads();
    const int n0 = blockIdx.x * 32 + ty * 8;
    float acc[8] = {0.f, 0.f, 0.f, 0.f, 0.f, 0.f, 0.f, 0.f};
    if (n0 + 8 <= N_NODES) {
        for (int k = 0; k < FIN; k += 4) {
            float4 xv[8];
#pragma unroll
            for (int i = 0; i < 8; ++i)
                xv[i] = *(const float4*)(x + (size_t)(n0 + i) * FIN + k);
#pragma unroll
            for (int kk = 0; kk < 4; ++kk) {
                float w = Wl[k + kk][tx];
#pragma unroll
                for (int i = 0; i < 8; ++i) {
                    float xs = (kk == 0) ? xv[i].x : (kk == 1) ? xv[i].y : (kk == 2) ? xv[i].z : xv[i].w;
                    acc[i] = fmaf(xs, w, acc[i]);
                }
            }
        }
    } else {
        for (int i = 0; i < 8; ++i) {
            if (n0 + i >= N_NODES) break;
            const float* xr = x + (size_t)(n0 + i) * FIN;
            float a = 0.f;
            for (int k = 0; k < FIN; ++k) a = fmaf(xr[k], Wl[k][tx], a);
            acc[i] = a;
        }
    }
    int f = f0 + tx;
    if (f < FOUT) {
#pragma unroll
        for (int i = 0; i < 8; ++i)
            if (n0 + i < N_NODES) h[(size_t)(n0 + i) * FOUT + f] = f2bf(acc[i]);
    }
}

// ---------------- per-(node,head) attention logits (uint4 = 8 bf16 loads) ----------------
__global__ void al_kernel(const unsigned short* __restrict__ h, const float* __restrict__ a_s,
                          const float* __restrict__ a_d, float* __restrict__ al_s,
                          float* __restrict__ al_d, int H, int C) {
    int i = blockIdx.x * blockDim.x + threadIdx.x;   // n*H + head
    if (i >= N_NODES * H) return;
    int n = i / H, hd = i % H;
    const unsigned short* hr = h + (size_t)n * H * C + hd * C;
    const float* as = a_s + hd * C;
    const float* ad = a_d + hd * C;
    float s1 = 0.f, s2 = 0.f;
    for (int c = 0; c < C; c += 8) {
        uint4 q = *(const uint4*)(hr + c);
        float2 p0 = bfp2(q.x), p1 = bfp2(q.y), p2 = bfp2(q.z), p3 = bfp2(q.w);
        s1 = fmaf(p0.x, as[c], s1);     s2 = fmaf(p0.x, ad[c], s2);
        s1 = fmaf(p0.y, as[c + 1], s1); s2 = fmaf(p0.y, ad[c + 1], s2);
        s1 = fmaf(p1.x, as[c + 2], s1); s2 = fmaf(p1.x, ad[c + 2], s2);
        s1 = fmaf(p1.y, as[c + 3], s1); s2 = fmaf(p1.y, ad[c + 3], s2);
        s1 = fmaf(p2.x, as[c + 4], s1); s2 = fmaf(p2.x, ad[c + 4], s2);
        s1 = fmaf(p2.y, as[c + 5], s1); s2 = fmaf(p2.y, ad[c + 5], s2);
        s1 = fmaf(p3.x, as[c + 6], s1); s2 = fmaf(p3.x, ad[c + 6], s2);
        s1 = fmaf(p3.y, as[c + 7], s1); s2 = fmaf(p3.y, ad[c + 7], s2);
    }
    al_s[i] = s1; al_d[i] = s2;
}

// ---------------- CSR build ----------------
__global__ void deg_kernel(const int* __restrict__ ei, int* __restrict__ deg) {
    int e = blockIdx.x * 256 + threadIdx.x;
    if (e >= N_EDGES) return;
    atomicAdd(&deg[ei[N_EDGES + e]], 1);
}

__global__ void scan_kernel(int* __restrict__ deg, int* __restrict__ rowptr) {
    __shared__ int sums[1024];
    int t = threadIdx.x;
    const int PER = (N_NODES + 1023) / 1024;  // 49
    int base = t * PER;
    int s = 0;
    for (int i = 0; i < PER; ++i) { int idx = base + i; if (idx < N_NODES) s += deg[idx]; }
    sums[t] = s;
    __syncthreads();
    for (int off = 1; off < 1024; off <<= 1) {
        int v = sums[t];
        int add = (t >= off) ? sums[t - off] : 0;
        __syncthreads();
        sums[t] = v + add;
        __syncthreads();
    }
    if (t == 0) rowptr[N_NODES] = sums[1023];
    int run = (t == 0) ? 0 : sums[t - 1];
    for (int i = 0; i < PER; ++i) {
        int idx = base + i;
        if (idx < N_NODES) {
            int d = deg[idx];
            rowptr[idx] = run;
            deg[idx] = run;       // cursor starts at row begin
            run += d;
        }
    }
}

__global__ void scatter_kernel(const int* __restrict__ ei, int* __restrict__ cursor,
                               unsigned short* __restrict__ csr_src) {
    int e = blockIdx.x * 256 + threadIdx.x;
    if (e >= N_EDGES) return;
    int src = ei[e], dst = ei[N_EDGES + e];
    int pos = atomicAdd(&cursor[dst], 1);
    csr_src[pos] = (unsigned short)src;   // N_NODES < 65536
}

// ---------------- gather aggregation, one wave per node ----------------
// HC = 64 (H=4, C=16): lane = channel; fused bias + ELU epilogue. 8x unrolled.
__global__ void agg64_kernel(const int* __restrict__ rowptr, const unsigned short* __restrict__ csr_src,
                             const float* __restrict__ al_s, const float* __restrict__ al_d,
                             const unsigned short* __restrict__ hb, const float* __restrict__ b,
                             float* __restrict__ xn) {
    int node = blockIdx.x * 4 + (threadIdx.x >> 6);
    int lane = threadIdx.x & 63;
    if (node >= N_NODES) return;
    int hd = lane >> 4;                           // C = 16
    float ald = al_d[node * 4 + hd];
    int beg = rowptr[node], end = rowptr[node + 1];
    float w = expf(lrelu02(al_s[node * 4 + hd] + ald));
    float denom = w;
    float acc = w * bf2f(hb[(size_t)node * 64 + lane]);
    int j = beg;
    for (; j + 8 <= end; j += 8) {
        int s[8];
        unsigned short q[8];
#pragma unroll
        for (int u = 0; u < 8; ++u) s[u] = csr_src[j + u];
#pragma unroll
        for (int u = 0; u < 8; ++u) q[u] = hb[(size_t)s[u] * 64 + lane];
        float wv[8];
#pragma unroll
        for (int u = 0; u < 8; ++u) wv[u] = expf(lrelu02(al_s[s[u] * 4 + hd] + ald));
#pragma unroll
        for (int u = 0; u < 8; ++u) {
            denom += wv[u];
            acc = fmaf(wv[u], bf2f(q[u]), acc);
        }
    }
    for (; j < end; ++j) {
        int s0 = csr_src[j];
        float w0 = expf(lrelu02(al_s[s0 * 4 + hd] + ald));
        denom += w0;
        acc = fmaf(w0, bf2f(hb[(size_t)s0 * 64 + lane]), acc);
    }
    xn[(size_t)node * 64 + lane] = elu1(acc / denom + b[lane]);
}

// HC = 240 (H=6, C=40): lane handles 4 channels (8B bf16 gather); 8x unrolled.
__global__ void agg240_kernel(const int* __restrict__ rowptr, const unsigned short* __restrict__ csr_src,
                              const float* __restrict__ al_s, const float* __restrict__ al_d,
                              const unsigned short* __restrict__ hb, float* __restrict__ out) {
    int node = blockIdx.x * 4 + (threadIdx.x >> 6);
    int lane = threadIdx.x & 63;
    if (node >= N_NODES) return;
    bool act = lane < 60;
    int c0 = act ? lane * 4 : 0;
    int hd = c0 / 40;
    float ald = al_d[node * 6 + hd];
    int beg = rowptr[node], end = rowptr[node + 1];
    float w = expf(lrelu02(al_s[node * 6 + hd] + ald));
    float denom = w;
    float4 acc;
    {
        uint2 q = *(const uint2*)(hb + (size_t)node * 240 + c0);
        float2 ab = bfp2(q.x), cd = bfp2(q.y);
        acc.x = w * ab.x; acc.y = w * ab.y; acc.z = w * cd.x; acc.w = w * cd.y;
    }
    int j = beg;
    for (; j + 8 <= end; j += 8) {
        int s[8];
        uint2 q[8];
#pragma unroll
        for (int u = 0; u < 8; ++u) s[u] = csr_src[j + u];
#pragma unroll
        for (int u = 0; u < 8; ++u) q[u] = *(const uint2*)(hb + (size_t)s[u] * 240 + c0);
        float wv[8];
#pragma unroll
        for (int u = 0; u < 8; ++u) wv[u] = expf(lrelu02(al_s[s[u] * 6 + hd] + ald));
#pragma unroll
        for (int u = 0; u < 8; ++u) {
            denom += wv[u];
            float2 ab = bfp2(q[u].x), cd = bfp2(q[u].y);
            acc.x = fmaf(wv[u], ab.x, acc.x); acc.y = fmaf(wv[u], ab.y, acc.y);
            acc.z = fmaf(wv[u], cd.x, acc.z); acc.w = fmaf(wv[u], cd.y, acc.w);
        }
    }
    for (; j < end; ++j) {
        int s0 = csr_src[j];
        uint2 q0 = *(const uint2*)(hb + (size_t)s0 * 240 + c0);
        float w0 = expf(lrelu02(al_s[s0 * 6 + hd] + ald));
        denom += w0;
        float2 ab = bfp2(q0.x), cd = bfp2(q0.y);
        acc.x = fmaf(w0, ab.x, acc.x); acc.y = fmaf(w0, ab.y, acc.y);
        acc.z = fmaf(w0, cd.x, acc.z); acc.w = fmaf(w0, cd.y, acc.w);
    }
    if (act) {
        float r = 1.f / denom;
        float* op = out + (size_t)node * 240 + c0;
        op[0] = acc.x * r; op[1] = acc.y * r; op[2] = acc.z * r; op[3] = acc.w * r;
    }
}

// ---------------- layer-3 epilogue: head-mean + bias + ELU + log_softmax ----------------
__global__ void final_kernel(const float* __restrict__ out3, const float* __restrict__ b3,
                             float* __restrict__ y) {
    int node = blockIdx.x * 4 + (threadIdx.x >> 6);
    int lane = threadIdx.x & 63;
    if (node >= N_NODES) return;
    float v;
    if (lane < 40) {
        const float* p = out3 + (size_t)node * 240;
        float s = 0.f;
#pragma unroll
        for (int hh = 0; hh < 6; ++hh) s += p[hh * 40 + lane];
        v = s * (1.f / 6.f) + b3[lane];
        v = elu1(v);
    } else {
        v = -INFINITY;
    }
    float m = v;
#pragma unroll
    for (int o = 32; o > 0; o >>= 1) m = fmaxf(m, __shfl_xor(m, o));
    float ex = (lane < 40) ? expf(v - m) : 0.f;
    float ssum = ex;
#pragma unroll
    for (int o = 32; o > 0; o >>= 1) ssum += __shfl_xor(ssum, o);
    if (lane < 40) y[(size_t)node * 40 + lane] = v - m - logf(ssum);
}

extern "C" void kernel_launch(void* const* d_in, const int* in_sizes, int n_in,
                              void* d_out, int out_size, void* d_ws, size_t ws_size,
                              hipStream_t stream) {
    const float* x   = (const float*)d_in[0];
    const int*   ei  = (const int*)d_in[1];   // [2, E]
    const float* W1  = (const float*)d_in[2];
    const float* a1s = (const float*)d_in[3];
    const float* a1d = (const float*)d_in[4];
    const float* b1  = (const float*)d_in[5];
    const float* W2  = (const float*)d_in[6];
    const float* a2s = (const float*)d_in[7];
    const float* a2d = (const float*)d_in[8];
    const float* b2  = (const float*)d_in[9];
    const float* W3  = (const float*)d_in[10];
    const float* a3s = (const float*)d_in[11];
    const float* a3d = (const float*)d_in[12];
    const float* b3  = (const float*)d_in[13];
    float* y = (float*)d_out;

    float* ws      = (float*)d_ws;
    unsigned short* h_bf = (unsigned short*)ws;           // 12,000,000 ushort (= 6.0M floats)
    float* out_buf = ws + 6000000;                        // 12,000,000 floats
    float* x_buf   = ws + 18000000;                       //  3,200,000
    float* al_s    = ws + 21200000;                       //    300,000
    float* al_d    = ws + 21500000;                       //    300,000
    int*   deg     = (int*)(ws + 21800000);               //     50,000 (becomes cursor)
    int*   rowptr  = (int*)(ws + 21850000);               //     50,001
    unsigned short* csr_src = (unsigned short*)(ws + 21900008); // 1.6M ushort
    // total: 22,700,008 floats = 90.8 MB

    // ---- CSR build (once; shared by all 3 layers) ----
    hipMemsetAsync(deg, 0, N_NODES * sizeof(int), stream);
    deg_kernel<<<(N_EDGES + 255) / 256, 256, 0, stream>>>(ei, deg);
    scan_kernel<<<1, 1024, 0, stream>>>(deg, rowptr);
    scatter_kernel<<<(N_EDGES + 255) / 256, 256, 0, stream>>>(ei, deg, csr_src);

    const int agg_grid = (N_NODES + 3) / 4;
    const int gemm_gx = (N_NODES + 31) / 32;

    // ---- layer 1: 128 -> (4,16) concat ----
    {
        dim3 gblk(64, 4), ggrd(gemm_gx, 1);
        gemm_kernel<128><<<ggrd, gblk, 0, stream>>>(x, W1, h_bf, 64);
        al_kernel<<<(N_NODES * 4 + 255) / 256, 256, 0, stream>>>(h_bf, a1s, a1d, al_s, al_d, 4, 16);
        agg64_kernel<<<agg_grid, 256, 0, stream>>>(rowptr, csr_src, al_s, al_d, h_bf, b1, x_buf);
    }

    // ---- layer 2: 64 -> (4,16) concat ----
    {
        dim3 gblk(64, 4), ggrd(gemm_gx, 1);
        gemm_kernel<64><<<ggrd, gblk, 0, stream>>>(x_buf, W2, h_bf, 64);
        al_kernel<<<(N_NODES * 4 + 255) / 256, 256, 0, stream>>>(h_bf, a2s, a2d, al_s, al_d, 4, 16);
        agg64_kernel<<<agg_grid, 256, 0, stream>>>(rowptr, csr_src, al_s, al_d, h_bf, b2, x_buf);
    }

    // ---- layer 3: 64 -> (6,40) mean ----
    {
        dim3 gblk(64, 4), ggrd(gemm_gx, 4);
        gemm_kernel<64><<<ggrd, gblk, 0, stream>>>(x_buf, W3, h_bf, 240);
        al_kernel<<<(N_NODES * 6 + 255) / 256, 256, 0, stream>>>(h_bf, a3s, a3d, al_s, al_d, 6, 40);
        agg240_kernel<<<agg_grid, 256, 0, stream>>>(rowptr, csr_src, al_s, al_d, h_bf, out_buf);
        final_kernel<<<agg_grid, 256, 0, stream>>>(out_buf, b3, y);
    }
}

// Round 5
// 864.997 us; speedup vs baseline: 10.0919x; 1.1298x over previous
//
#include <hip/hip_runtime.h>
#include <math.h>

#define N_NODES 50000
#define N_EDGES 1600000

__device__ __forceinline__ float lrelu02(float x) { return x > 0.f ? x : 0.2f * x; }
__device__ __forceinline__ float elu1(float x)    { return x > 0.f ? x : expm1f(x); }

// bf16 helpers (RNE pack)
__device__ __forceinline__ unsigned short f2bf(float f) {
    unsigned int u = __float_as_uint(f);
    return (unsigned short)((u + 0x7fffu + ((u >> 16) & 1u)) >> 16);
}
__device__ __forceinline__ float bf2f(unsigned short s) {
    return __uint_as_float((unsigned int)s << 16);
}
__device__ __forceinline__ float2 bfp2(unsigned int u) {
    float2 r;
    r.x = __uint_as_float(u << 16);
    r.y = __uint_as_float(u & 0xffff0000u);
    return r;
}

// ---------------- GEMM (layers 1/2, FOUT=64): h_bf = bf16(x @ W) ----------------
// block (64,4); each thread: 8 nodes x 1 channel; writes are n*128B aligned lines.
template<int FIN>
__global__ void gemm_kernel(const float* __restrict__ x, const float* __restrict__ W,
                            unsigned short* __restrict__ h, int FOUT) {
    __shared__ float Wl[FIN][64];
    const int tx = threadIdx.x, ty = threadIdx.y;
    for (int i = ty * 64 + tx; i < FIN * 64; i += 256) {
        int k = i >> 6, f = i & 63;
        Wl[k][f] = (f < FOUT) ? W[(size_t)k * FOUT + f] : 0.f;
    }
    __syncthreads();
    const int n0 = blockIdx.x * 32 + ty * 8;
    float acc[8] = {0.f, 0.f, 0.f, 0.f, 0.f, 0.f, 0.f, 0.f};
    if (n0 + 8 <= N_NODES) {
        for (int k = 0; k < FIN; k += 4) {
            float4 xv[8];
#pragma unroll
            for (int i = 0; i < 8; ++i)
                xv[i] = *(const float4*)(x + (size_t)(n0 + i) * FIN + k);
#pragma unroll
            for (int kk = 0; kk < 4; ++kk) {
                float w = Wl[k + kk][tx];
#pragma unroll
                for (int i = 0; i < 8; ++i) {
                    float xs = (kk == 0) ? xv[i].x : (kk == 1) ? xv[i].y : (kk == 2) ? xv[i].z : xv[i].w;
                    acc[i] = fmaf(xs, w, acc[i]);
                }
            }
        }
    } else {
        for (int i = 0; i < 8; ++i) {
            if (n0 + i >= N_NODES) break;
            const float* xr = x + (size_t)(n0 + i) * FIN;
            float a = 0.f;
            for (int k = 0; k < FIN; ++k) a = fmaf(xr[k], Wl[k][tx], a);
            acc[i] = a;
        }
    }
    if (tx < FOUT) {
#pragma unroll
        for (int i = 0; i < 8; ++i)
            if (n0 + i < N_NODES) h[(size_t)(n0 + i) * FOUT + tx] = f2bf(acc[i]);
    }
}

// ---------------- L3 GEMM: h[n,240] = bf16(x[n,64] @ W[64,240]), fused al3 ----------------
// 32 nodes/block; W fully in LDS (61.4 KB); output staged in LDS bf16 tile;
// contiguous aligned writeout; al_s/al_d computed from the LDS tile.
__global__ void gemm240_kernel(const float* __restrict__ x, const float* __restrict__ W,
                               const float* __restrict__ a_s, const float* __restrict__ a_d,
                               unsigned short* __restrict__ h,
                               float* __restrict__ al_s, float* __restrict__ al_d) {
    __shared__ float Wl[64][240];           // 61440 B
    __shared__ unsigned short ot[32][240];  // 15360 B
    const int tx = threadIdx.x, ty = threadIdx.y;
    const int tid = ty * 64 + tx;
    {   // stage W (flat layout identical to [64][240] row-major)
        const float4* W4 = (const float4*)W;
        float4* Wl4 = (float4*)&Wl[0][0];
        for (int i = tid; i < 64 * 240 / 4; i += 256) Wl4[i] = W4[i];
    }
    __syncthreads();
    const int n0b = blockIdx.x * 32;
    const int n0 = n0b + ty * 8;
    float acc[4][8];
#pragma unroll
    for (int g = 0; g < 4; ++g)
#pragma unroll
        for (int i = 0; i < 8; ++i) acc[g][i] = 0.f;
    const int tx3 = (tx < 48) ? (192 + tx) : 0;   // clamped col for partial group
    if (n0 + 8 <= N_NODES) {
        for (int k = 0; k < 64; k += 4) {
            float4 xv[8];
#pragma unroll
            for (int i = 0; i < 8; ++i)
                xv[i] = *(const float4*)(x + (size_t)(n0 + i) * 64 + k);
#pragma unroll
            for (int kk = 0; kk < 4; ++kk) {
                float w0 = Wl[k + kk][tx];
                float w1 = Wl[k + kk][64 + tx];
                float w2 = Wl[k + kk][128 + tx];
                float w3 = Wl[k + kk][tx3];
#pragma unroll
                for (int i = 0; i < 8; ++i) {
                    float xs = (kk == 0) ? xv[i].x : (kk == 1) ? xv[i].y : (kk == 2) ? xv[i].z : xv[i].w;
                    acc[0][i] = fmaf(xs, w0, acc[0][i]);
                    acc[1][i] = fmaf(xs, w1, acc[1][i]);
                    acc[2][i] = fmaf(xs, w2, acc[2][i]);
                    acc[3][i] = fmaf(xs, w3, acc[3][i]);
                }
            }
        }
    } else {
        for (int i = 0; i < 8; ++i) {
            if (n0 + i >= N_NODES) break;
            const float* xr = x + (size_t)(n0 + i) * 64;
            for (int k = 0; k < 64; ++k) {
                float xs = xr[k];
                acc[0][i] = fmaf(xs, Wl[k][tx], acc[0][i]);
                acc[1][i] = fmaf(xs, Wl[k][64 + tx], acc[1][i]);
                acc[2][i] = fmaf(xs, Wl[k][128 + tx], acc[2][i]);
                acc[3][i] = fmaf(xs, Wl[k][tx3], acc[3][i]);
            }
        }
    }
    // stage into LDS bf16 tile
#pragma unroll
    for (int i = 0; i < 8; ++i) {
        ot[ty * 8 + i][tx] = f2bf(acc[0][i]);
        ot[ty * 8 + i][64 + tx] = f2bf(acc[1][i]);
        ot[ty * 8 + i][128 + tx] = f2bf(acc[2][i]);
        if (tx < 48) ot[ty * 8 + i][192 + tx] = f2bf(acc[3][i]);
    }
    __syncthreads();
    // contiguous aligned writeout: rows of 480B, block chunk = 15360B
    int vrows = N_NODES - n0b; if (vrows > 32) vrows = 32;
    {
        const unsigned int* po = (const unsigned int*)&ot[0][0];
        unsigned int* ph = (unsigned int*)(h + (size_t)n0b * 240);
        int limit = vrows * 120;
        for (int i = tid; i < limit; i += 256) ph[i] = po[i];
    }
    // fused al3: thread t<192 -> (node, head); 40-elem dot from LDS tile
    if (tid < 192) {
        int node = tid / 6, hd = tid % 6;
        if (node < vrows) {
            const unsigned short* r = &ot[node][hd * 40];
            const float* as = a_s + hd * 40;
            const float* ad = a_d + hd * 40;
            float s1 = 0.f, s2 = 0.f;
            for (int c = 0; c < 40; c += 2) {
                unsigned int q = *(const unsigned int*)(r + c);
                float2 p = bfp2(q);
                s1 = fmaf(p.x, as[c], s1);     s2 = fmaf(p.x, ad[c], s2);
                s1 = fmaf(p.y, as[c + 1], s1); s2 = fmaf(p.y, ad[c + 1], s2);
            }
            al_s[(n0b + node) * 6 + hd] = s1;
            al_d[(n0b + node) * 6 + hd] = s2;
        }
    }
}

// ---------------- per-(node,head) attention logits (layers 1/2) ----------------
__global__ void al_kernel(const unsigned short* __restrict__ h, const float* __restrict__ a_s,
                          const float* __restrict__ a_d, float* __restrict__ al_s,
                          float* __restrict__ al_d, int H, int C) {
    int i = blockIdx.x * blockDim.x + threadIdx.x;   // n*H + head
    if (i >= N_NODES * H) return;
    int n = i / H, hd = i % H;
    const unsigned short* hr = h + (size_t)n * H * C + hd * C;
    const float* as = a_s + hd * C;
    const float* ad = a_d + hd * C;
    float s1 = 0.f, s2 = 0.f;
    for (int c = 0; c < C; c += 8) {
        uint4 q = *(const uint4*)(hr + c);
        float2 p0 = bfp2(q.x), p1 = bfp2(q.y), p2 = bfp2(q.z), p3 = bfp2(q.w);
        s1 = fmaf(p0.x, as[c], s1);     s2 = fmaf(p0.x, ad[c], s2);
        s1 = fmaf(p0.y, as[c + 1], s1); s2 = fmaf(p0.y, ad[c + 1], s2);
        s1 = fmaf(p1.x, as[c + 2], s1); s2 = fmaf(p1.x, ad[c + 2], s2);
        s1 = fmaf(p1.y, as[c + 3], s1); s2 = fmaf(p1.y, ad[c + 3], s2);
        s1 = fmaf(p2.x, as[c + 4], s1); s2 = fmaf(p2.x, ad[c + 4], s2);
        s1 = fmaf(p2.y, as[c + 5], s1); s2 = fmaf(p2.y, ad[c + 5], s2);
        s1 = fmaf(p3.x, as[c + 6], s1); s2 = fmaf(p3.x, ad[c + 6], s2);
        s1 = fmaf(p3.y, as[c + 7], s1); s2 = fmaf(p3.y, ad[c + 7], s2);
    }
    al_s[i] = s1; al_d[i] = s2;
}

// ---------------- CSR build ----------------
__global__ void deg_kernel(const int* __restrict__ ei, int* __restrict__ deg) {
    int e = blockIdx.x * 256 + threadIdx.x;
    if (e >= N_EDGES) return;
    atomicAdd(&deg[ei[N_EDGES + e]], 1);
}

__global__ void scan_kernel(int* __restrict__ deg, int* __restrict__ rowptr) {
    __shared__ int sums[1024];
    int t = threadIdx.x;
    const int PER = (N_NODES + 1023) / 1024;  // 49
    int base = t * PER;
    int s = 0;
    for (int i = 0; i < PER; ++i) { int idx = base + i; if (idx < N_NODES) s += deg[idx]; }
    sums[t] = s;
    __syncthreads();
    for (int off = 1; off < 1024; off <<= 1) {
        int v = sums[t];
        int add = (t >= off) ? sums[t - off] : 0;
        __syncthreads();
        sums[t] = v + add;
        __syncthreads();
    }
    if (t == 0) rowptr[N_NODES] = sums[1023];
    int run = (t == 0) ? 0 : sums[t - 1];
    for (int i = 0; i < PER; ++i) {
        int idx = base + i;
        if (idx < N_NODES) {
            int d = deg[idx];
            rowptr[idx] = run;
            deg[idx] = run;       // cursor starts at row begin
            run += d;
        }
    }
}

__global__ void scatter_kernel(const int* __restrict__ ei, int* __restrict__ cursor,
                               unsigned short* __restrict__ csr_src) {
    int e = blockIdx.x * 256 + threadIdx.x;
    if (e >= N_EDGES) return;
    int src = ei[e], dst = ei[N_EDGES + e];
    int pos = atomicAdd(&cursor[dst], 1);
    csr_src[pos] = (unsigned short)src;   // N_NODES < 65536
}

// ---------------- gather aggregation, one wave per node ----------------
// HC = 64 (H=4, C=16): lane = channel; fused bias + ELU epilogue. 8x unrolled.
__global__ void agg64_kernel(const int* __restrict__ rowptr, const unsigned short* __restrict__ csr_src,
                             const float* __restrict__ al_s, const float* __restrict__ al_d,
                             const unsigned short* __restrict__ hb, const float* __restrict__ b,
                             float* __restrict__ xn) {
    int node = blockIdx.x * 4 + (threadIdx.x >> 6);   // grid exact: N_NODES % 4 == 0
    int lane = threadIdx.x & 63;
    int hd = lane >> 4;                               // C = 16
    float ald = al_d[node * 4 + hd];
    int beg = rowptr[node], end = rowptr[node + 1];
    float w = expf(lrelu02(al_s[node * 4 + hd] + ald));
    float denom = w;
    float acc = w * bf2f(hb[(size_t)node * 64 + lane]);
    int j = beg;
    for (; j + 8 <= end; j += 8) {
        int s[8];
        unsigned short q[8];
#pragma unroll
        for (int u = 0; u < 8; ++u) s[u] = csr_src[j + u];
#pragma unroll
        for (int u = 0; u < 8; ++u) q[u] = hb[(size_t)s[u] * 64 + lane];
        float wv[8];
#pragma unroll
        for (int u = 0; u < 8; ++u) wv[u] = expf(lrelu02(al_s[s[u] * 4 + hd] + ald));
#pragma unroll
        for (int u = 0; u < 8; ++u) {
            denom += wv[u];
            acc = fmaf(wv[u], bf2f(q[u]), acc);
        }
    }
    for (; j < end; ++j) {
        int s0 = csr_src[j];
        float w0 = expf(lrelu02(al_s[s0 * 4 + hd] + ald));
        denom += w0;
        acc = fmaf(w0, bf2f(hb[(size_t)s0 * 64 + lane]), acc);
    }
    xn[(size_t)node * 64 + lane] = elu1(acc / denom + b[lane]);
}

// HC = 240 (H=6, C=40): lane handles 4 channels; 8x unrolled; FUSED final epilogue
// (head-mean + bias + ELU + log_softmax) via per-wave LDS tile.
__global__ void agg240_kernel(const int* __restrict__ rowptr, const unsigned short* __restrict__ csr_src,
                              const float* __restrict__ al_s, const float* __restrict__ al_d,
                              const unsigned short* __restrict__ hb, const float* __restrict__ b3,
                              float* __restrict__ y) {
    __shared__ float sh[4][240];
    int wv_id = threadIdx.x >> 6;
    int node = blockIdx.x * 4 + wv_id;                // grid exact: 12500 blocks
    int lane = threadIdx.x & 63;
    bool act = lane < 60;
    int c0 = act ? lane * 4 : 0;
    int hd = c0 / 40;
    float ald = al_d[node * 6 + hd];
    int beg = rowptr[node], end = rowptr[node + 1];
    float w = expf(lrelu02(al_s[node * 6 + hd] + ald));
    float denom = w;
    float4 acc;
    {
        uint2 q = *(const uint2*)(hb + (size_t)node * 240 + c0);
        float2 ab = bfp2(q.x), cd = bfp2(q.y);
        acc.x = w * ab.x; acc.y = w * ab.y; acc.z = w * cd.x; acc.w = w * cd.y;
    }
    int j = beg;
    for (; j + 8 <= end; j += 8) {
        int s[8];
        uint2 q[8];
#pragma unroll
        for (int u = 0; u < 8; ++u) s[u] = csr_src[j + u];
#pragma unroll
        for (int u = 0; u < 8; ++u) q[u] = *(const uint2*)(hb + (size_t)s[u] * 240 + c0);
        float wvv[8];
#pragma unroll
        for (int u = 0; u < 8; ++u) wvv[u] = expf(lrelu02(al_s[s[u] * 6 + hd] + ald));
#pragma unroll
        for (int u = 0; u < 8; ++u) {
            denom += wvv[u];
            float2 ab = bfp2(q[u].x), cd = bfp2(q[u].y);
            acc.x = fmaf(wvv[u], ab.x, acc.x); acc.y = fmaf(wvv[u], ab.y, acc.y);
            acc.z = fmaf(wvv[u], cd.x, acc.z); acc.w = fmaf(wvv[u], cd.y, acc.w);
        }
    }
    for (; j < end; ++j) {
        int s0 = csr_src[j];
        uint2 q0 = *(const uint2*)(hb + (size_t)s0 * 240 + c0);
        float w0 = expf(lrelu02(al_s[s0 * 6 + hd] + ald));
        denom += w0;
        float2 ab = bfp2(q0.x), cd = bfp2(q0.y);
        acc.x = fmaf(w0, ab.x, acc.x); acc.y = fmaf(w0, ab.y, acc.y);
        acc.z = fmaf(w0, cd.x, acc.z); acc.w = fmaf(w0, cd.y, acc.w);
    }
    if (act) {
        float r = 1.f / denom;
        float* sp = &sh[wv_id][c0];
        sp[0] = acc.x * r; sp[1] = acc.y * r; sp[2] = acc.z * r; sp[3] = acc.w * r;
    }
    __syncthreads();
    // final: head-mean + bias + ELU + log_softmax over 40 classes
    float v;
    if (lane < 40) {
        const float* p = sh[wv_id];
        float s = 0.f;
#pragma unroll
        for (int hh = 0; hh < 6; ++hh) s += p[hh * 40 + lane];
        v = elu1(s * (1.f / 6.f) + b3[lane]);
    } else {
        v = -INFINITY;
    }
    float m = v;
#pragma unroll
    for (int o = 32; o > 0; o >>= 1) m = fmaxf(m, __shfl_xor(m, o));
    float ex = (lane < 40) ? expf(v - m) : 0.f;
    float ssum = ex;
#pragma unroll
    for (int o = 32; o > 0; o >>= 1) ssum += __shfl_xor(ssum, o);
    if (lane < 40) y[(size_t)node * 40 + lane] = v - m - logf(ssum);
}

extern "C" void kernel_launch(void* const* d_in, const int* in_sizes, int n_in,
                              void* d_out, int out_size, void* d_ws, size_t ws_size,
                              hipStream_t stream) {
    const float* x   = (const float*)d_in[0];
    const int*   ei  = (const int*)d_in[1];   // [2, E]
    const float* W1  = (const float*)d_in[2];
    const float* a1s = (const float*)d_in[3];
    const float* a1d = (const float*)d_in[4];
    const float* b1  = (const float*)d_in[5];
    const float* W2  = (const float*)d_in[6];
    const float* a2s = (const float*)d_in[7];
    const float* a2d = (const float*)d_in[8];
    const float* b2  = (const float*)d_in[9];
    const float* W3  = (const float*)d_in[10];
    const float* a3s = (const float*)d_in[11];
    const float* a3d = (const float*)d_in[12];
    const float* b3  = (const float*)d_in[13];
    float* y = (float*)d_out;

    float* ws      = (float*)d_ws;
    unsigned short* h_bf = (unsigned short*)ws;           // 12,000,000 ushort (= 6.0M floats)
    float* x_buf   = ws + 6000000;                        //  3,200,000
    float* al_s    = ws + 9200000;                        //    300,000
    float* al_d    = ws + 9500000;                        //    300,000
    int*   deg     = (int*)(ws + 9800000);                //     50,000 (becomes cursor)
    int*   rowptr  = (int*)(ws + 9850000);                //     50,001
    unsigned short* csr_src = (unsigned short*)(ws + 9900008); // 1.6M ushort
    // total: 10,700,008 floats = 42.8 MB

    // ---- CSR build (once; shared by all 3 layers) ----
    hipMemsetAsync(deg, 0, N_NODES * sizeof(int), stream);
    deg_kernel<<<(N_EDGES + 255) / 256, 256, 0, stream>>>(ei, deg);
    scan_kernel<<<1, 1024, 0, stream>>>(deg, rowptr);
    scatter_kernel<<<(N_EDGES + 255) / 256, 256, 0, stream>>>(ei, deg, csr_src);

    const int agg_grid = N_NODES / 4;              // 12500, exact
    const int gemm_gx = (N_NODES + 31) / 32;

    // ---- layer 1: 128 -> (4,16) concat ----
    {
        dim3 gblk(64, 4), ggrd(gemm_gx, 1);
        gemm_kernel<128><<<ggrd, gblk, 0, stream>>>(x, W1, h_bf, 64);
        al_kernel<<<(N_NODES * 4 + 255) / 256, 256, 0, stream>>>(h_bf, a1s, a1d, al_s, al_d, 4, 16);
        agg64_kernel<<<agg_grid, 256, 0, stream>>>(rowptr, csr_src, al_s, al_d, h_bf, b1, x_buf);
    }

    // ---- layer 2: 64 -> (4,16) concat ----
    {
        dim3 gblk(64, 4), ggrd(gemm_gx, 1);
        gemm_kernel<64><<<ggrd, gblk, 0, stream>>>(x_buf, W2, h_bf, 64);
        al_kernel<<<(N_NODES * 4 + 255) / 256, 256, 0, stream>>>(h_bf, a2s, a2d, al_s, al_d, 4, 16);
        agg64_kernel<<<agg_grid, 256, 0, stream>>>(rowptr, csr_src, al_s, al_d, h_bf, b2, x_buf);
    }

    // ---- layer 3: 64 -> (6,40) mean; gemm fused with al3, agg fused with final ----
    {
        dim3 gblk(64, 4), ggrd(gemm_gx, 1);
        gemm240_kernel<<<ggrd, gblk, 0, stream>>>(x_buf, W3, a3s, a3d, h_bf, al_s, al_d);
        agg240_kernel<<<agg_grid, 256, 0, stream>>>(rowptr, csr_src, al_s, al_d, h_bf, b3, y);
    }
}